// Round 7
// baseline (711.305 us; speedup 1.0000x reference)
//
#include <hip/hip_runtime.h>
#include <math.h>

#define TT 65536
#define DD 256
#define EE 8
#define HH 512
#define OO 256
#define NN 4096   // E*H

typedef unsigned int u32;
typedef unsigned short u16;
typedef __attribute__((ext_vector_type(4))) float f32x4;
typedef __attribute__((ext_vector_type(16))) float f32x16;
typedef __attribute__((ext_vector_type(2))) u32 u32x2;
typedef __attribute__((ext_vector_type(4))) u32 u32x4;
typedef __attribute__((ext_vector_type(8))) __bf16 bf16x8;

__device__ __forceinline__ u16 f2bf(float f) {
    u32 u = __builtin_bit_cast(u32, f);
    u32 r = (u + 0x7fffu + ((u >> 16) & 1u)) >> 16;
    return (u16)r;
}

__device__ __forceinline__ u32 cvt_pk_bf16(float lo, float hi) {
    u32 r;
    asm("v_cvt_pk_bf16_f32 %0, %1, %2" : "=v"(r) : "v"(lo), "v"(hi));
    return r;
}

__device__ __forceinline__ bf16x8 ld_frag(const void* p) {
    u32x4 v = *(const u32x4*)p;
    return __builtin_bit_cast(bf16x8, v);
}

__device__ __forceinline__ float gelu_fast(float v) {
    float t = v * v;
    float u = __builtin_fmaf(t, -0.1029479f, -2.3022075f);
    float z = v * u;
    float e = __builtin_amdgcn_exp2f(z);
    return v * __builtin_amdgcn_rcpf(1.0f + e);
}

// ---------------- weight conversions ----------------
// w1 [E][D][H] f32 -> w1t [N=e*512+h][D] bf16
__global__ __launch_bounds__(256) void k_conv_w1(const float* __restrict__ w1, u16* __restrict__ w1t) {
    int i = blockIdx.x * 256 + threadIdx.x;            // < 1M, i = ((e*512+h)*256)+d
    int d = i & 255, h = (i >> 8) & 511, e = i >> 17;
    w1t[i] = f2bf(w1[((size_t)e << 17) + ((size_t)d << 9) + h]);
}
// w2 [E][H][O] f32 -> w2t [O][K2=e*512+h] bf16
__global__ __launch_bounds__(256) void k_conv_w2t(const float* __restrict__ w2, u16* __restrict__ w2t) {
    int i = blockIdx.x * 256 + threadIdx.x;            // < 1M, i = o*4096 + k2
    int k2 = i & 4095, o = i >> 12;
    int e = k2 >> 9, h = k2 & 511;
    w2t[i] = f2bf(w2[((size_t)e << 17) + ((size_t)h << 8) + o]);
}

// ---------------- gating ----------------
__global__ __launch_bounds__(256) void k_gating(const float* __restrict__ x,
                                                const float* __restrict__ gw,
                                                const float* __restrict__ gb,
                                                float* __restrict__ wt,
                                                double* __restrict__ part) {
    __shared__ float gws[DD * EE];
    __shared__ float gbs[EE];
    __shared__ double red[256];
    int tid = threadIdx.x;
    for (int i = tid; i < DD * EE; i += 256) gws[i] = gw[i];
    if (tid < EE) gbs[tid] = gb[tid];
    __syncthreads();

    int t = blockIdx.x * 256 + tid;
    double l[EE];
#pragma unroll
    for (int e = 0; e < EE; ++e) l[e] = (double)gbs[e];

    const f32x4* xr = (const f32x4*)(x + (size_t)t * DD);
    for (int d4 = 0; d4 < DD / 4; ++d4) {
        f32x4 xv = xr[d4];
#pragma unroll
        for (int j = 0; j < 4; ++j) {
            double xs = (double)xv[j];
            int d = d4 * 4 + j;
#pragma unroll
            for (int e = 0; e < EE; ++e) l[e] += xs * (double)gws[d * EE + e];
        }
    }
    double mx = l[0];
#pragma unroll
    for (int e = 1; e < EE; ++e) mx = l[e] > mx ? l[e] : mx;
    double p[EE], s = 0.0;
#pragma unroll
    for (int e = 0; e < EE; ++e) { p[e] = exp(l[e] - mx); s += p[e]; }
    double inv = 1.0 / s;
    double ent = 0.0;
#pragma unroll
    for (int e = 0; e < EE; ++e) { p[e] *= inv; ent += p[e] * log(p[e] + 1e-8); }

    bool mask[EE];
#pragma unroll
    for (int e = 0; e < EE; ++e) {
        double c = 0.0; int rk = 0;
#pragma unroll
        for (int f = 0; f < EE; ++f) {
            bool before = (p[f] > p[e]) || (p[f] == p[e] && f < e);
            if (before) { c += p[f]; rk++; }
        }
        c += p[e];
        mask[e] = (c <= 0.7) || (rk == 0);
    }
    double ms = 0.0;
#pragma unroll
    for (int e = 0; e < EE; ++e) if (mask[e]) ms += p[e];
    double inv2 = 1.0 / ms;
#pragma unroll
    for (int e = 0; e < EE; ++e) wt[(size_t)e * TT + t] = (float)(mask[e] ? p[e] * inv2 : 0.0);

    red[tid] = -ent;
    __syncthreads();
    for (int st = 128; st > 0; st >>= 1) {
        if (tid < st) red[tid] += red[tid + st];
        __syncthreads();
    }
    if (tid == 0) part[blockIdx.x] = red[0];
}

__global__ __launch_bounds__(256) void k_final(const double* __restrict__ part, float* __restrict__ loss) {
    __shared__ double red[256];
    int tid = threadIdx.x;
    red[tid] = part[tid];
    __syncthreads();
    for (int st = 128; st > 0; st >>= 1) {
        if (tid < st) red[tid] += red[tid + st];
        __syncthreads();
    }
    if (tid == 0) loss[0] = (float)(red[0] / (double)TT);
}

// ---------------- GEMM 1: H[t][n] = gelu(X @ W1t^T + b1) * wt ----------------
// Block: 128 tok x 256 n, 512 thr (8 waves). K=256 in 4 quarters of 64, W double-buffered.
// Wave = 64n x 64tok (2x2 of 32x32x16). A=W1 (LDS), B=X (LDS): D rows=n(regs), cols=tok(lane).
// LDS: Xs 64K @0 | Wq0 32K @64K | Wq1 32K @96K | wgt 512B @128K.
__global__ __launch_bounds__(512) void k_g1(const float* __restrict__ x,
                                            const u16* __restrict__ w1t,
                                            const float* __restrict__ b1,
                                            const float* __restrict__ wtg,
                                            u16* __restrict__ Hbuf, int tc0) {
    __shared__ __align__(16) unsigned char smem[131584];
    float* wgt = (float*)(smem + 131072);

    const int tid = threadIdx.x;
    const int wid = tid >> 6, lane = tid & 63, l31 = lane & 31, lg2 = lane >> 5;
    const int ts = wid & 1, ns = wid >> 1;             // tok strip (2x64), n strip (4x64)
    const int tb = blockIdx.x >> 4, nb = blockIdx.x & 15;
    const int t0 = tb * 128;
    const int e = nb >> 1;

    // stage Xs: f32 -> bf16, rows 512B, swizzle ^((row&15)<<4)
    {
        const float* xb = x + (size_t)(tc0 + t0) * DD;
#pragma unroll
        for (int i = 0; i < 8; ++i) {
            int L = i * 8192 + tid * 16;
            int row = L >> 9, elem = (L & 511) >> 1;
            const float* src = xb + row * DD + elem;
            f32x4 a = *(const f32x4*)src;
            f32x4 b = *(const f32x4*)(src + 4);
            u32x4 o;
            o.x = cvt_pk_bf16(a[0], a[1]); o.y = cvt_pk_bf16(a[2], a[3]);
            o.z = cvt_pk_bf16(b[0], b[1]); o.w = cvt_pk_bf16(b[2], b[3]);
            *(u32x4*)(smem + (L ^ ((row & 15) << 4))) = o;
        }
    }
    if (tid < 128) wgt[tid] = wtg[(size_t)e * TT + tc0 + t0 + tid];
    // stage W quarter 0: [256 n rows][64 k], rows 128B, swizzle ^((row&7)<<4)
    {
        const u16* wsrc = w1t + (size_t)nb * 256 * DD;
#pragma unroll
        for (int i = 0; i < 4; ++i) {
            int flat = tid * 4 + i, row = flat >> 3, slot = flat & 7;
            u32x4 v = *(const u32x4*)(wsrc + (size_t)row * DD + slot * 8);
            *(u32x4*)(smem + 65536 + ((row * 128 + slot * 16) ^ ((row & 7) << 4))) = v;
        }
    }
    __syncthreads();

    f32x16 acc[2][2];          // [m: n-sub 32][t: tok-sub 32]
#pragma unroll
    for (int m = 0; m < 2; ++m)
#pragma unroll
        for (int t = 0; t < 2; ++t) acc[m][t] = (f32x16)0.0f;

#pragma unroll 1
    for (int q = 0; q < 4; ++q) {
        // T14: issue next-quarter W loads early
        u32x4 st0, st1, st2, st3;
        if (q < 3) {
            const u16* wsrc = w1t + (size_t)nb * 256 * DD + (q + 1) * 64;
            int flat = tid * 4;
            int row0 = flat >> 3, slot0 = flat & 7;
            st0 = *(const u32x4*)(wsrc + (size_t)row0 * DD + slot0 * 8);
            st1 = *(const u32x4*)(wsrc + (size_t)((flat + 1) >> 3) * DD + ((flat + 1) & 7) * 8);
            st2 = *(const u32x4*)(wsrc + (size_t)((flat + 2) >> 3) * DD + ((flat + 2) & 7) * 8);
            st3 = *(const u32x4*)(wsrc + (size_t)((flat + 3) >> 3) * DD + ((flat + 3) & 7) * 8);
        }
        const unsigned char* W = smem + ((q & 1) ? 98304 : 65536);
        const int arow = ns * 64 + l31;
        const int xrow = ts * 64 + l31;
        const int asz = (arow & 7) << 4;
        const int xsz = (xrow & 15) << 4;
#pragma unroll
        for (int ks = 0; ks < 4; ++ks) {
            int ab = arow * 128 + ks * 32 + lg2 * 16;
            bf16x8 a0 = ld_frag(W + (ab ^ asz));
            bf16x8 a1 = ld_frag(W + ((ab + 32 * 128) ^ asz));
            int bb = xrow * 512 + q * 128 + ks * 32 + lg2 * 16;
            bf16x8 b0 = ld_frag(smem + (bb ^ xsz));
            bf16x8 b1v = ld_frag(smem + ((bb + 32 * 512) ^ xsz));
            acc[0][0] = __builtin_amdgcn_mfma_f32_32x32x16_bf16(a0, b0, acc[0][0], 0, 0, 0);
            acc[0][1] = __builtin_amdgcn_mfma_f32_32x32x16_bf16(a0, b1v, acc[0][1], 0, 0, 0);
            acc[1][0] = __builtin_amdgcn_mfma_f32_32x32x16_bf16(a1, b0, acc[1][0], 0, 0, 0);
            acc[1][1] = __builtin_amdgcn_mfma_f32_32x32x16_bf16(a1, b1v, acc[1][1], 0, 0, 0);
        }
        if (q < 3) {
            unsigned char* Wn = smem + ((q & 1) ? 65536 : 98304);
            int flat = tid * 4;
#pragma unroll
            for (int i = 0; i < 4; ++i) {
                int f = flat + i, row = f >> 3, slot = f & 7;
                u32x4 v = (i == 0) ? st0 : (i == 1) ? st1 : (i == 2) ? st2 : st3;
                *(u32x4*)(Wn + ((row * 128 + slot * 16) ^ ((row & 7) << 4))) = v;
            }
        }
        __syncthreads();
    }

    // epilogue: gelu(acc+b1)*wgt -> bf16 tile in smem (reuse Xs region), then linear global write
#pragma unroll
    for (int m = 0; m < 2; ++m) {
        const float* b1p = b1 + nb * 256 + ns * 64 + m * 32 + lg2 * 4;
        f32x4 bbv[4];
#pragma unroll
        for (int qq = 0; qq < 4; ++qq) bbv[qq] = *(const f32x4*)(b1p + qq * 8);
#pragma unroll
        for (int t = 0; t < 2; ++t) {
            int tok = ts * 64 + t * 32 + l31;
            float w = wgt[tok];
#pragma unroll
            for (int qq = 0; qq < 4; ++qq) {
                float g[4];
#pragma unroll
                for (int r = 0; r < 4; ++r)
                    g[r] = gelu_fast(acc[m][t][qq * 4 + r] + bbv[qq][r]) * w;
                u32x2 pk;
                pk.x = cvt_pk_bf16(g[0], g[1]);
                pk.y = cvt_pk_bf16(g[2], g[3]);
                int nl = ns * 64 + m * 32 + qq * 8 + lg2 * 4;
                int byt = tok * 512 + nl * 2;
                *(u32x2*)(smem + (byt ^ ((tok & 15) << 4))) = pk;
            }
        }
    }
    __syncthreads();
    {
        u16* hb = Hbuf + (size_t)t0 * NN + nb * 256;
#pragma unroll
        for (int i = 0; i < 8; ++i) {
            int off = i * 8192 + tid * 16;
            int row = off >> 9, colb = off & 511;
            u32x4 v = *(const u32x4*)(smem + (off ^ ((row & 15) << 4)));
            *(u32x4*)(hb + (size_t)row * NN + (colb >> 1)) = v;
        }
    }
}

// ---------------- GEMM 2: out[t][o] = H @ W2t^T + sum_e wt*b2 ----------------
// Block: 128 tok x 128 o, 256 thr (4 waves). K=4096, BK=64, double-buffered A/B tiles.
// Wave = 64tok x 64o (2x2 of 32x32x16). A=H rows(tok), B=W2t rows(o): D rows=tok, cols=o.
// LDS: A0 16K | A1 16K | B0 16K | B1 16K | wts 4K = 68K -> 2 blocks/CU.
__global__ __launch_bounds__(256) void k_g2(const u16* __restrict__ Hbuf,
                                            const u16* __restrict__ w2t,
                                            const float* __restrict__ b2,
                                            const float* __restrict__ wtg,
                                            float* __restrict__ out, int tc0) {
    __shared__ __align__(16) unsigned char smem[69632];
    float* wts = (float*)(smem + 65536);               // [E][128]

    const int tid = threadIdx.x;
    const int wid = tid >> 6, lane = tid & 63, l31 = lane & 31, lg2 = lane >> 5;
    const int tsm = wid & 1, osn = wid >> 1;
    const int tb = blockIdx.x >> 1, ob = blockIdx.x & 1;
    const int t0 = tb * 128;

    const u16* hsrc = Hbuf + (size_t)t0 * NN;
    const u16* wsrc = w2t + (size_t)(ob * 128) * NN;

    // stage wts + K-step 0
#pragma unroll
    for (int j = 0; j < 4; ++j) {
        int i = j * 256 + tid;
        wts[i] = wtg[(size_t)(i >> 7) * TT + tc0 + t0 + (i & 127)];
    }
#pragma unroll
    for (int i = 0; i < 4; ++i) {
        int flat = tid * 4 + i, row = flat >> 3, slot = flat & 7;
        u32x4 va = *(const u32x4*)(hsrc + (size_t)row * NN + slot * 8);
        u32x4 vb = *(const u32x4*)(wsrc + (size_t)row * NN + slot * 8);
        int off = (row * 128 + slot * 16) ^ ((row & 7) << 4);
        *(u32x4*)(smem + off) = va;
        *(u32x4*)(smem + 32768 + off) = vb;
    }
    __syncthreads();

    f32x16 acc[2][2];
#pragma unroll
    for (int m = 0; m < 2; ++m)
#pragma unroll
        for (int n = 0; n < 2; ++n) acc[m][n] = (f32x16)0.0f;

#pragma unroll 1
    for (int kk = 0; kk < 64; ++kk) {
        u32x4 sa0, sa1, sa2, sa3, sb0, sb1, sb2, sb3;
        if (kk < 63) {
            const u16* ha = hsrc + (kk + 1) * 64;
            const u16* wa = wsrc + (kk + 1) * 64;
            int flat = tid * 4;
            sa0 = *(const u32x4*)(ha + (size_t)(flat >> 3) * NN + (flat & 7) * 8);
            sb0 = *(const u32x4*)(wa + (size_t)(flat >> 3) * NN + (flat & 7) * 8);
            sa1 = *(const u32x4*)(ha + (size_t)((flat + 1) >> 3) * NN + ((flat + 1) & 7) * 8);
            sb1 = *(const u32x4*)(wa + (size_t)((flat + 1) >> 3) * NN + ((flat + 1) & 7) * 8);
            sa2 = *(const u32x4*)(ha + (size_t)((flat + 2) >> 3) * NN + ((flat + 2) & 7) * 8);
            sb2 = *(const u32x4*)(wa + (size_t)((flat + 2) >> 3) * NN + ((flat + 2) & 7) * 8);
            sa3 = *(const u32x4*)(ha + (size_t)((flat + 3) >> 3) * NN + ((flat + 3) & 7) * 8);
            sb3 = *(const u32x4*)(wa + (size_t)((flat + 3) >> 3) * NN + ((flat + 3) & 7) * 8);
        }
        const unsigned char* A = smem + (kk & 1) * 16384;
        const unsigned char* B = smem + 32768 + (kk & 1) * 16384;
        const int hr = tsm * 64 + l31, wr = osn * 64 + l31;
        const int hsz = (hr & 7) << 4, wsz = (wr & 7) << 4;
#pragma unroll
        for (int ks = 0; ks < 4; ++ks) {
            int ab = hr * 128 + ks * 32 + lg2 * 16;
            bf16x8 A0 = ld_frag(A + (ab ^ hsz));
            bf16x8 A1 = ld_frag(A + ((ab + 4096) ^ hsz));
            int bb = wr * 128 + ks * 32 + lg2 * 16;
            bf16x8 B0 = ld_frag(B + (bb ^ wsz));
            bf16x8 B1 = ld_frag(B + ((bb + 4096) ^ wsz));
            acc[0][0] = __builtin_amdgcn_mfma_f32_32x32x16_bf16(A0, B0, acc[0][0], 0, 0, 0);
            acc[0][1] = __builtin_amdgcn_mfma_f32_32x32x16_bf16(A0, B1, acc[0][1], 0, 0, 0);
            acc[1][0] = __builtin_amdgcn_mfma_f32_32x32x16_bf16(A1, B0, acc[1][0], 0, 0, 0);
            acc[1][1] = __builtin_amdgcn_mfma_f32_32x32x16_bf16(A1, B1, acc[1][1], 0, 0, 0);
        }
        if (kk < 63) {
            unsigned char* An = smem + ((kk + 1) & 1) * 16384;
            unsigned char* Bn = smem + 32768 + ((kk + 1) & 1) * 16384;
            int flat = tid * 4;
#pragma unroll
            for (int i = 0; i < 4; ++i) {
                int f = flat + i, row = f >> 3, slot = f & 7;
                int off = (row * 128 + slot * 16) ^ ((row & 7) << 4);
                u32x4 va = (i == 0) ? sa0 : (i == 1) ? sa1 : (i == 2) ? sa2 : sa3;
                u32x4 vb = (i == 0) ? sb0 : (i == 1) ? sb1 : (i == 2) ? sb2 : sb3;
                *(u32x4*)(An + off) = va;
                *(u32x4*)(Bn + off) = vb;
            }
        }
        __syncthreads();
    }

    // epilogue: + sum_e wts[e][tok]*b2[e][o], store f32
#pragma unroll
    for (int n = 0; n < 2; ++n) {
        int o = ob * 128 + osn * 64 + n * 32 + l31;
        float b2v[EE];
#pragma unroll
        for (int e = 0; e < EE; ++e) b2v[e] = b2[e * OO + o];
#pragma unroll
        for (int m = 0; m < 2; ++m) {
#pragma unroll
            for (int r = 0; r < 16; ++r) {
                int tok = tsm * 64 + m * 32 + (r & 3) + 8 * (r >> 2) + 4 * lg2;
                float wb = 0.f;
#pragma unroll
                for (int e = 0; e < EE; ++e) wb += wts[e * 128 + tok] * b2v[e];
                out[(size_t)(tc0 + t0 + tok) * OO + o] = acc[m][n][r] + wb;
            }
        }
    }
}

extern "C" void kernel_launch(void* const* d_in, const int* in_sizes, int n_in,
                              void* d_out, int out_size, void* d_ws, size_t ws_size,
                              hipStream_t stream) {
    const float* x  = (const float*)d_in[0];
    const float* gw = (const float*)d_in[1];
    const float* gb = (const float*)d_in[2];
    const float* w1 = (const float*)d_in[3];
    const float* b1 = (const float*)d_in[4];
    const float* w2 = (const float*)d_in[5];
    const float* b2 = (const float*)d_in[6];
    float* out = (float*)d_out;

    char* ws = (char*)d_ws;
    u16* w1t    = (u16*)(ws);                    // 2 MB
    u16* w2t    = (u16*)(ws + 2097152);          // 2 MB
    float* wt   = (float*)(ws + 4194304);        // 2 MB ([E][T])
    double* prt = (double*)(ws + 6291456);       // 2 KB
    u16* Hbuf   = (u16*)(ws + 8388608);          // chunk*4096*2 B

    size_t base = 8388608;
    int chunk;
    if (ws_size >= base + (size_t)16384 * NN * 2) chunk = 16384;       // 128 MB H
    else if (ws_size >= base + (size_t)4096 * NN * 2) chunk = 4096;    // 32 MB H
    else chunk = 1024;                                                 // 8 MB H

    k_conv_w1<<<(EE * HH * DD) / 256, 256, 0, stream>>>(w1, w1t);
    k_conv_w2t<<<(OO * NN) / 256, 256, 0, stream>>>(w2, w2t);
    k_gating<<<TT / 256, 256, 0, stream>>>(x, gw, gb, wt, prt);

    for (int tc0 = 0; tc0 < TT; tc0 += chunk) {
        k_g1<<<(chunk / 128) * 16, 512, 0, stream>>>(x, w1t, b1, wt, Hbuf, tc0);
        k_g2<<<(chunk / 128) * 2, 256, 0, stream>>>(Hbuf, w2t, b2, wt, out, tc0);
    }
    k_final<<<1, 256, 0, stream>>>(prt, out + (size_t)TT * OO);
}

// Round 8
// 512.530 us; speedup vs baseline: 1.3878x; 1.3878x over previous
//
#include <hip/hip_runtime.h>
#include <math.h>

#define TT 65536
#define DD 256
#define EE 8
#define HH 512
#define OO 256
#define NN 4096

typedef unsigned int u32;
typedef unsigned short u16;
typedef __attribute__((ext_vector_type(4))) float f32x4;
typedef __attribute__((ext_vector_type(16))) float f32x16;
typedef __attribute__((ext_vector_type(2))) u32 u32x2;
typedef __attribute__((ext_vector_type(4))) u32 u32x4;
typedef __attribute__((ext_vector_type(8))) __bf16 bf16x8;

__device__ __forceinline__ u16 f2bf(float f) {
    u32 u = __builtin_bit_cast(u32, f);
    u32 r = (u + 0x7fffu + ((u >> 16) & 1u)) >> 16;
    return (u16)r;
}

__device__ __forceinline__ u32 cvt_pk_bf16(float lo, float hi) {
    u32 r;
    asm("v_cvt_pk_bf16_f32 %0, %1, %2" : "=v"(r) : "v"(lo), "v"(hi));
    return r;
}

__device__ __forceinline__ bf16x8 ld_frag(const void* p) {
    u32x4 v = *(const u32x4*)p;
    return __builtin_bit_cast(bf16x8, v);
}

__device__ __forceinline__ float gelu_fast(float v) {
    float t = v * v;
    float u = __builtin_fmaf(t, -0.1029479f, -2.3022075f);
    float z = v * u;
    float e = __builtin_amdgcn_exp2f(z);
    return v * __builtin_amdgcn_rcpf(1.0f + e);
}

// ---------------- weight conversions to fragment-major layout ----------------
// w1 [E][D][H] f32 -> w1s [nb=n>>5][kb=k>>4][l=n&31][j=k&15] bf16 (n=e*512+h, k=d)
__global__ __launch_bounds__(256) void k_conv_w1(const float* __restrict__ w1, u16* __restrict__ w1s) {
    int i = blockIdx.x * 256 + threadIdx.x;            // < 1M
    int j = i & 15, l = (i >> 4) & 31, kb = (i >> 9) & 15, nb = i >> 13;
    int n = nb * 32 + l, k = kb * 16 + j;
    int e = n >> 9, h = n & 511;
    w1s[i] = f2bf(w1[(size_t)e * 131072 + (size_t)k * 512 + h]);
}
// w2 [E][H][O] f32 -> w2s [ob=o>>5][kb2=k2>>4][l=o&31][j=k2&15] bf16 (k2=e*512+h)
__global__ __launch_bounds__(256) void k_conv_w2(const float* __restrict__ w2, u16* __restrict__ w2s) {
    int i = blockIdx.x * 256 + threadIdx.x;            // < 1M
    int j = i & 15, l = (i >> 4) & 31, kb2 = (i >> 9) & 255, ob = i >> 17;
    int o = ob * 32 + l, k2 = kb2 * 16 + j;
    int e = k2 >> 9, h = k2 & 511;
    w2s[i] = f2bf(w2[(size_t)e * 131072 + (size_t)h * 256 + o]);
}

// ---------------- gating ----------------
__global__ __launch_bounds__(256) void k_gating(const float* __restrict__ x,
                                                const float* __restrict__ gw,
                                                const float* __restrict__ gb,
                                                float* __restrict__ wt,
                                                double* __restrict__ part) {
    __shared__ float gws[DD * EE];
    __shared__ float gbs[EE];
    __shared__ double red[256];
    int tid = threadIdx.x;
    for (int i = tid; i < DD * EE; i += 256) gws[i] = gw[i];
    if (tid < EE) gbs[tid] = gb[tid];
    __syncthreads();

    int t = blockIdx.x * 256 + tid;
    double l[EE];
#pragma unroll
    for (int e = 0; e < EE; ++e) l[e] = (double)gbs[e];

    const f32x4* xr = (const f32x4*)(x + (size_t)t * DD);
    for (int d4 = 0; d4 < DD / 4; ++d4) {
        f32x4 xv = xr[d4];
#pragma unroll
        for (int j = 0; j < 4; ++j) {
            double xs = (double)xv[j];
            int d = d4 * 4 + j;
#pragma unroll
            for (int e = 0; e < EE; ++e) l[e] += xs * (double)gws[d * EE + e];
        }
    }
    double mx = l[0];
#pragma unroll
    for (int e = 1; e < EE; ++e) mx = l[e] > mx ? l[e] : mx;
    double p[EE], s = 0.0;
#pragma unroll
    for (int e = 0; e < EE; ++e) { p[e] = exp(l[e] - mx); s += p[e]; }
    double inv = 1.0 / s;
    double ent = 0.0;
#pragma unroll
    for (int e = 0; e < EE; ++e) { p[e] *= inv; ent += p[e] * log(p[e] + 1e-8); }

    bool mask[EE];
#pragma unroll
    for (int e = 0; e < EE; ++e) {
        double c = 0.0; int rk = 0;
#pragma unroll
        for (int f = 0; f < EE; ++f) {
            bool before = (p[f] > p[e]) || (p[f] == p[e] && f < e);
            if (before) { c += p[f]; rk++; }
        }
        c += p[e];
        mask[e] = (c <= 0.7) || (rk == 0);
    }
    double ms = 0.0;
#pragma unroll
    for (int e = 0; e < EE; ++e) if (mask[e]) ms += p[e];
    double inv2 = 1.0 / ms;
#pragma unroll
    for (int e = 0; e < EE; ++e) wt[(size_t)e * TT + t] = (float)(mask[e] ? p[e] * inv2 : 0.0);

    red[tid] = -ent;
    __syncthreads();
    for (int st = 128; st > 0; st >>= 1) {
        if (tid < st) red[tid] += red[tid + st];
        __syncthreads();
    }
    if (tid == 0) part[blockIdx.x] = red[0];
}

__global__ __launch_bounds__(256) void k_final(const double* __restrict__ part, float* __restrict__ loss) {
    __shared__ double red[256];
    int tid = threadIdx.x;
    red[tid] = part[tid];
    __syncthreads();
    for (int st = 128; st > 0; st >>= 1) {
        if (tid < st) red[tid] += red[tid + st];
        __syncthreads();
    }
    if (tid == 0) loss[0] = (float)(red[0] / (double)TT);
}

// ---------------- fused MoE MLP (v8) ----------------
// 128 tok/block, 512 thr (8 waves). 32 chunks of 128 h (e = c>>2). Hs double-buffered,
// ONE barrier per chunk: { G1(c) [Xs + global W1] ; hwrite -> Hs[c&1] ; BAR ; G2(c) [Hs + global W2] }.
// G1: wave = 32h x 64tok (hs=wid&3, th=wid>>2): per ks 1 global A + 2 LDS B -> 2 MFMA.
// G2: wave = 64tok x 64o (os=wid&3, tq=wid>>2): per ks 2 LDS A + 2 global B -> 4 MFMA.
// LDS: Xs 64K | Hs0 32K | Hs1 32K | wts 4K = 132K -> 1 block/CU.
__global__ __launch_bounds__(512, 2) void k_moe(const float* __restrict__ x,
                                                const u16* __restrict__ w1s,
                                                const u16* __restrict__ w2s,
                                                const float* __restrict__ b1,
                                                const float* __restrict__ b2,
                                                const float* __restrict__ wtg,
                                                float* __restrict__ out) {
    __shared__ __align__(16) unsigned char smem[135168];
    float* wts = (float*)(smem + 131072);              // [E][128]

    const int tid = threadIdx.x;
    const int wid = tid >> 6;
    const int lane = tid & 63;
    const int l31 = lane & 31;
    const int lg2 = lane >> 5;
    const int hs = wid & 3, th = wid >> 2;             // G1 roles
    const int os = wid & 3, tq = wid >> 2;             // G2 roles
    const int t0 = blockIdx.x * 128;

    // stage Xs: f32 -> bf16, rows 512B, swizzle ^((row&15)<<4)
    {
        const float* xb = x + (size_t)t0 * DD;
#pragma unroll
        for (int i = 0; i < 8; ++i) {
            int L = i * 8192 + tid * 16;
            int row = L >> 9, elem = (L & 511) >> 1;
            const float* src = xb + (size_t)row * DD + elem;
            f32x4 a = *(const f32x4*)src;
            f32x4 b = *(const f32x4*)(src + 4);
            u32x4 o;
            o.x = cvt_pk_bf16(a[0], a[1]); o.y = cvt_pk_bf16(a[2], a[3]);
            o.z = cvt_pk_bf16(b[0], b[1]); o.w = cvt_pk_bf16(b[2], b[3]);
            *(u32x4*)(smem + (L ^ ((row & 15) << 4))) = o;
        }
    }
    {
        int i0 = tid;
        wts[i0] = wtg[(size_t)(i0 >> 7) * TT + t0 + (i0 & 127)];
        int i1 = tid + 512;
        wts[i1] = wtg[(size_t)(i1 >> 7) * TT + t0 + (i1 & 127)];
    }
    __syncthreads();

    f32x16 oacc[2][2];
#pragma unroll
    for (int m = 0; m < 2; ++m)
#pragma unroll
        for (int n = 0; n < 2; ++n) oacc[m][n] = (f32x16)0.0f;

    // G1 X addressing (constant across chunks)
    const int tokA = th * 64 + l31;        // t=0
    const int tokB = th * 64 + 32 + l31;   // t=1
    const int xbA = tokA * 512 + lg2 * 16, xszA = (tokA & 15) << 4;
    const int xbB = tokB * 512 + lg2 * 16, xszB = (tokB & 15) << 4;
    // G2 Hs addressing
    const int hrA = tq * 64 + l31;         // m=0 token row
    const int hrB = tq * 64 + 32 + l31;    // m=1
    const int hbA = hrA * 256 + lg2 * 16, hszA = (hrA & 15) << 4;
    const int hbB = hrB * 256 + lg2 * 16, hszB = (hrB & 15) << 4;
    const int lfrag = l31 * 16 + lg2 * 8;  // lane offset within 512-elem frag

#pragma unroll 1
    for (int c = 0; c < 32; ++c) {
        const int e = c >> 2;
        unsigned char* Hc = smem + 65536 + (c & 1) * 32768;

        // ---- G1: hf[t] = W1[32h] x X[32tok], K=256
        f32x16 hf[2];
        hf[0] = (f32x16)0.0f;
        hf[1] = (f32x16)0.0f;
        const u16* w1p = w1s + ((size_t)(c * 4 + hs) * 16) * 512 + lfrag;
#pragma unroll 4
        for (int ks = 0; ks < 16; ++ks) {
            bf16x8 a = ld_frag(w1p + ks * 512);
            bf16x8 b0 = ld_frag(smem + ((xbA + ks * 32) ^ xszA));
            bf16x8 b1 = ld_frag(smem + ((xbB + ks * 32) ^ xszB));
            hf[0] = __builtin_amdgcn_mfma_f32_32x32x16_bf16(a, b0, hf[0], 0, 0, 0);
            hf[1] = __builtin_amdgcn_mfma_f32_32x32x16_bf16(a, b1, hf[1], 0, 0, 0);
        }
        // epilogue: +b1, gelu, *wgt, pack -> Hs[c&1] (rows = tok, 256B, swizzled)
        {
            const float* b1p = b1 + c * 128 + hs * 32 + lg2 * 4;
            f32x4 bbv[4];
#pragma unroll
            for (int q = 0; q < 4; ++q) bbv[q] = *(const f32x4*)(b1p + q * 8);
#pragma unroll
            for (int t = 0; t < 2; ++t) {
                int tok = th * 64 + t * 32 + l31;
                float wgt = wts[e * 128 + tok];
#pragma unroll
                for (int q = 0; q < 4; ++q) {
                    float g[4];
#pragma unroll
                    for (int r = 0; r < 4; ++r)
                        g[r] = gelu_fast(hf[t][q * 4 + r] + bbv[q][r]) * wgt;
                    u32x2 pk;
                    pk.x = cvt_pk_bf16(g[0], g[1]);
                    pk.y = cvt_pk_bf16(g[2], g[3]);
                    int byt = tok * 256 + hs * 64 + q * 16 + lg2 * 8;
                    *(u32x2*)(Hc + (byt ^ ((tok & 15) << 4))) = pk;
                }
            }
        }
        __syncthreads();
        // ---- G2: oacc[m][n] += Hs[64tok] x W2[64o], K=128
        const u16* w2p0 = w2s + ((size_t)(os * 2) * 256 + c * 8) * 512 + lfrag;
        const u16* w2p1 = w2p0 + (size_t)256 * 512;
#pragma unroll 4
        for (int ks = 0; ks < 8; ++ks) {
            bf16x8 A0 = ld_frag(Hc + ((hbA + ks * 32) ^ hszA));
            bf16x8 A1 = ld_frag(Hc + ((hbB + ks * 32) ^ hszB));
            bf16x8 B0 = ld_frag(w2p0 + ks * 512);
            bf16x8 B1 = ld_frag(w2p1 + ks * 512);
            oacc[0][0] = __builtin_amdgcn_mfma_f32_32x32x16_bf16(A0, B0, oacc[0][0], 0, 0, 0);
            oacc[0][1] = __builtin_amdgcn_mfma_f32_32x32x16_bf16(A0, B1, oacc[0][1], 0, 0, 0);
            oacc[1][0] = __builtin_amdgcn_mfma_f32_32x32x16_bf16(A1, B0, oacc[1][0], 0, 0, 0);
            oacc[1][1] = __builtin_amdgcn_mfma_f32_32x32x16_bf16(A1, B1, oacc[1][1], 0, 0, 0);
        }
    }

    // epilogue: add sum_e wts[e][tok]*b2[e][o], store
#pragma unroll
    for (int n = 0; n < 2; ++n) {
        int o = os * 64 + n * 32 + l31;
        float b2v[EE];
#pragma unroll
        for (int e = 0; e < EE; ++e) b2v[e] = b2[e * OO + o];
#pragma unroll
        for (int m = 0; m < 2; ++m) {
#pragma unroll
            for (int r = 0; r < 16; ++r) {
                int tok = tq * 64 + m * 32 + (r & 3) + 8 * (r >> 2) + 4 * lg2;
                float wb = 0.f;
#pragma unroll
                for (int e = 0; e < EE; ++e) wb += wts[e * 128 + tok] * b2v[e];
                out[(size_t)(t0 + tok) * OO + o] = oacc[m][n][r] + wb;
            }
        }
    }
}

extern "C" void kernel_launch(void* const* d_in, const int* in_sizes, int n_in,
                              void* d_out, int out_size, void* d_ws, size_t ws_size,
                              hipStream_t stream) {
    const float* x  = (const float*)d_in[0];
    const float* gw = (const float*)d_in[1];
    const float* gb = (const float*)d_in[2];
    const float* w1 = (const float*)d_in[3];
    const float* b1 = (const float*)d_in[4];
    const float* w2 = (const float*)d_in[5];
    const float* b2 = (const float*)d_in[6];
    float* out = (float*)d_out;

    char* ws = (char*)d_ws;
    u16* w1s    = (u16*)(ws);                    // 2 MB
    u16* w2s    = (u16*)(ws + 2097152);          // 2 MB
    float* wt   = (float*)(ws + 4194304);        // 2 MB ([E][T])
    double* prt = (double*)(ws + 6291456);       // 2 KB

    k_conv_w1<<<(EE * HH * DD) / 256, 256, 0, stream>>>(w1, w1s);
    k_conv_w2<<<(OO * NN) / 256, 256, 0, stream>>>(w2, w2s);
    k_gating<<<TT / 256, 256, 0, stream>>>(x, gw, gb, wt, prt);
    k_moe<<<TT / 128, 512, 0, stream>>>(x, w1s, w2s, b1, b2, wt, out);
    k_final<<<1, 256, 0, stream>>>(prt, out + (size_t)TT * OO);
}